// Round 5
// baseline (217.383 us; speedup 1.0000x reference)
//
#include <hip/hip_runtime.h>
#include <hip/hip_bf16.h>

// ---------------------------------------------------------------------------
// CosineAttention forward.  b=16, c=512, h=w=32 -> seq=1024, heads=8, hd=64.
//
// Pipeline (all matmuls bf16 MFMA 16x16x32, fp32 accumulate):
//  1) wnorm_kernel : normalized bf16 w_attn (1536x512), w_proj (512x512)
//  2) xt_kernel    : x fp32 [b][c][s] -> x_t bf16 [b][s][c]
//  3) gemm_bf16<0> : xp[b][1536][1024] bf16 = wn_attn @ x   (B = x_t)
//  4) norm_pack    : fused pixel_norm + repack: q_sd,k_sd bf16 [bn][s][d]
//                    (Q gets 0.125*log2e), v_ds bf16 [bn][d][s]
//  5) attn_mfma    : flash attention, barrier-free: K/V A-frags read DIRECT
//                    from L2 (no LDS staging), defer-max, cvt_pk, setprio,
//                    XCD-local grid; writes y_t bf16 [b][s][ch]
//  6) gemm_bf16<1> : out = mp_add(x, wn_proj @ y)           (B = y_t)
// ---------------------------------------------------------------------------

typedef __attribute__((ext_vector_type(8))) short short8;
typedef __attribute__((ext_vector_type(4))) float f32x4;
typedef __attribute__((ext_vector_type(4))) unsigned short ushort4_t;

__device__ inline unsigned short f2bf(float v) {
  __hip_bfloat16 h = __float2bfloat16(v);
  return *reinterpret_cast<unsigned short*>(&h);
}
__device__ inline float bf2f(unsigned short u) {
  return __uint_as_float((unsigned)u << 16);
}
__device__ inline unsigned cvt_pk(float lo, float hi) {
  unsigned r;
  asm("v_cvt_pk_bf16_f32 %0, %1, %2" : "=v"(r) : "v"(lo), "v"(hi));
  return r;
}
__device__ inline void gload16(const void* g, void* l) {
  __builtin_amdgcn_global_load_lds(
      (const __attribute__((address_space(1))) unsigned int*)g,
      (__attribute__((address_space(3))) unsigned int*)l, 16, 0, 0);
}

// ---------------- weight normalization (bf16 out) --------------------------
__global__ __launch_bounds__(256) void wnorm_kernel(
    const float* __restrict__ wa, const float* __restrict__ wp,
    __hip_bfloat16* __restrict__ wna, __hip_bfloat16* __restrict__ wnp) {
  int o = blockIdx.x;
  const float* src;
  __hip_bfloat16* dst;
  if (o < 1536) { src = wa + (size_t)o * 512; dst = wna + (size_t)o * 512; }
  else          { src = wp + (size_t)(o - 1536) * 512; dst = wnp + (size_t)(o - 1536) * 512; }
  int tid = threadIdx.x;
  float a = src[tid], b = src[tid + 256];
  float ss = a * a + b * b;
#pragma unroll
  for (int off = 32; off > 0; off >>= 1) ss += __shfl_down(ss, off, 64);
  __shared__ float wsum[4];
  if ((tid & 63) == 0) wsum[tid >> 6] = ss;
  __syncthreads();
  float tot = wsum[0] + wsum[1] + wsum[2] + wsum[3];
  float r = 1.0f / (sqrtf(tot) + 2.2627416997969522e-3f);  // n + EPS*sqrt(512)
  dst[tid] = __float2bfloat16(a * r);
  dst[tid + 256] = __float2bfloat16(b * r);
}

// ---------------- x -> bf16 [b][s][c] transpose ----------------------------
__global__ __launch_bounds__(256) void xt_kernel(
    const float* __restrict__ x, __hip_bfloat16* __restrict__ xt) {
  __shared__ __align__(16) unsigned short trans[64][68];
  int s0 = blockIdx.x * 64, c0 = blockIdx.y * 64, b = blockIdx.z;
  int t = threadIdx.x;
  int sl = t & 63, cg = t >> 6;
  const float* src = x + (size_t)b * 524288 + (size_t)(c0 + cg * 16) * 1024 + s0 + sl;
#pragma unroll
  for (int i = 0; i < 16; i += 2) {
    float v0 = src[(size_t)i * 1024];
    float v1 = src[(size_t)(i + 1) * 1024];
    *(unsigned*)&trans[sl][cg * 16 + i] = (unsigned)f2bf(v0) | ((unsigned)f2bf(v1) << 16);
  }
  __syncthreads();
  int sw = t >> 2, cw = (t & 3) * 16;
  __hip_bfloat16* dst = xt + (size_t)b * 524288 + (size_t)(s0 + sw) * 512 + c0 + cw;
  uint2 r0 = *(uint2*)&trans[sw][cw + 0];
  uint2 r1 = *(uint2*)&trans[sw][cw + 4];
  uint2 r2 = *(uint2*)&trans[sw][cw + 8];
  uint2 r3 = *(uint2*)&trans[sw][cw + 12];
  uint4 o0 = {r0.x, r0.y, r1.x, r1.y};
  uint4 o1 = {r2.x, r2.y, r3.x, r3.y};
  *(uint4*)dst = o0;
  *(uint4*)((char*)dst + 16) = o1;
}

// ---------------- bf16 MFMA GEMM:  Out[b][M][1024] = A[Mx512] @ B[b]^T -----
// MODE 0: Out bf16 (QKV).  MODE 1: Out fp32 = mp_add(resid, acc).
template <int MODE>
__global__ __launch_bounds__(256) void gemm_bf16(
    const __hip_bfloat16* __restrict__ A, const __hip_bfloat16* __restrict__ B,
    void* __restrict__ Outv, const float* __restrict__ resid, int M) {
  __shared__ __align__(16) char Al[2][16384];
  __shared__ __align__(16) char Bl[2][16384];
  int t = threadIdx.x;
  int w = t >> 6, l = t & 63;
  int l15 = l & 15, lg = l >> 4;
  int wm = w >> 1, wn = w & 1;
  int n0 = blockIdx.x * 128, m0 = blockIdx.y * 128, b = blockIdx.z;
  const char* Ab = (const char*)A + (size_t)m0 * 1024;
  const char* Bb = (const char*)B + (size_t)b * 1048576 + (size_t)n0 * 1024;
  int rl = t >> 3;
  int soff = ((t & 7) * 16) ^ ((rl & 7) << 4);
  const char* asrc = Ab + (size_t)rl * 1024 + soff;
  const char* bsrc = Bb + (size_t)rl * 1024 + soff;

#define STAGE(bi, k0b)                                                    \
  do {                                                                    \
    _Pragma("unroll") for (int i = 0; i < 4; ++i) {                       \
      gload16(asrc + (size_t)i * 32768 + (k0b), Al[bi] + i * 4096 + w * 1024); \
      gload16(bsrc + (size_t)i * 32768 + (k0b), Bl[bi] + i * 4096 + w * 1024); \
    }                                                                     \
  } while (0)

  f32x4 acc[4][4];
#pragma unroll
  for (int mi = 0; mi < 4; ++mi)
#pragma unroll
    for (int ni = 0; ni < 4; ++ni) acc[mi][ni] = (f32x4){0.f, 0.f, 0.f, 0.f};

  STAGE(0, 0);
  __syncthreads();

  for (int ks = 0; ks < 8; ++ks) {
    int buf = ks & 1;
    if (ks < 7) STAGE(buf ^ 1, (ks + 1) * 128);
    short8 af[4][2], bf[4][2];
#pragma unroll
    for (int mi = 0; mi < 4; ++mi) {
      int row = wm * 64 + mi * 16 + l15;
      int sw = (row & 7) << 4;
#pragma unroll
      for (int h = 0; h < 2; ++h)
        af[mi][h] = *(const short8*)(Al[buf] + row * 128 + ((h * 64 + lg * 16) ^ sw));
    }
#pragma unroll
    for (int ni = 0; ni < 4; ++ni) {
      int row = wn * 64 + ni * 16 + l15;
      int sw = (row & 7) << 4;
#pragma unroll
      for (int h = 0; h < 2; ++h)
        bf[ni][h] = *(const short8*)(Bl[buf] + row * 128 + ((h * 64 + lg * 16) ^ sw));
    }
    __builtin_amdgcn_s_setprio(1);
#pragma unroll
    for (int mi = 0; mi < 4; ++mi)
#pragma unroll
      for (int ni = 0; ni < 4; ++ni) {
        acc[mi][ni] = __builtin_amdgcn_mfma_f32_16x16x32_bf16(af[mi][0], bf[ni][0], acc[mi][ni], 0, 0, 0);
        acc[mi][ni] = __builtin_amdgcn_mfma_f32_16x16x32_bf16(af[mi][1], bf[ni][1], acc[mi][ni], 0, 0, 0);
      }
    __builtin_amdgcn_s_setprio(0);
    if (ks < 7) __syncthreads();
  }
#undef STAGE

  if (MODE == 0) {
    unsigned short* outb = (unsigned short*)Outv + (size_t)b * M * 1024;
#pragma unroll
    for (int mi = 0; mi < 4; ++mi) {
      int row = m0 + wm * 64 + mi * 16 + lg * 4;
#pragma unroll
      for (int r = 0; r < 4; ++r) {
        unsigned short* orow = outb + (size_t)(row + r) * 1024 + n0 + wn * 64 + l15;
#pragma unroll
        for (int ni = 0; ni < 4; ++ni) orow[ni * 16] = f2bf(acc[mi][ni][r]);
      }
    }
  } else {
    float* outb = (float*)Outv + (size_t)b * M * 1024;
    const float* rb = resid + (size_t)b * M * 1024;
#pragma unroll
    for (int mi = 0; mi < 4; ++mi) {
      int row = m0 + wm * 64 + mi * 16 + lg * 4;
#pragma unroll
      for (int r = 0; r < 4; ++r) {
        float* orow = outb + (size_t)(row + r) * 1024 + n0 + wn * 64 + l15;
        const float* rrow = rb + (size_t)(row + r) * 1024 + n0 + wn * 64 + l15;
#pragma unroll
        for (int ni = 0; ni < 4; ++ni)
          orow[ni * 16] = 0.9191450300180578f * rrow[ni * 16] +
                          0.39391929857916763f * acc[mi][ni][r];
      }
    }
  }
}

// ---------------- fused pixel_norm + repack ---------------------------------
__global__ __launch_bounds__(256) void norm_pack(
    const __hip_bfloat16* __restrict__ xp,
    __hip_bfloat16* __restrict__ q_sd, __hip_bfloat16* __restrict__ k_sd,
    __hip_bfloat16* __restrict__ v_ds) {
  __shared__ __align__(16) unsigned short trans[64][68];
  int s0 = blockIdx.x * 64, g = blockIdx.y, b = blockIdx.z;
  int t = threadIdx.x;
  int s16 = t & 15, dg = t >> 4;
  int sl4 = s16 * 4;
  const unsigned short* src = (const unsigned short*)xp +
      (size_t)(b * 1536 + g * 512) * 1024 + s0 + sl4;
  float qm = (g == 0) ? 0.18033688011112042f : 1.0f;  // 0.125*log2(e) in Q

  ushort4_t raw[8][4];
  float f[4][4];
#pragma unroll
  for (int i = 0; i < 4; ++i) {
    int d = dg * 4 + i;
    float ss0 = 0.f, ss1 = 0.f, ss2 = 0.f, ss3 = 0.f;
#pragma unroll
    for (int n = 0; n < 8; ++n) {
      ushort4_t pk = *(const ushort4_t*)(src + (size_t)(n * 64 + d) * 1024);
      raw[n][i] = pk;
      float v0 = bf2f(pk[0]), v1 = bf2f(pk[1]), v2 = bf2f(pk[2]), v3 = bf2f(pk[3]);
      ss0 += v0 * v0; ss1 += v1 * v1; ss2 += v2 * v2; ss3 += v3 * v3;
    }
    f[i][0] = rsqrtf(ss0 * 0.125f + 1e-4f) * qm;
    f[i][1] = rsqrtf(ss1 * 0.125f + 1e-4f) * qm;
    f[i][2] = rsqrtf(ss2 * 0.125f + 1e-4f) * qm;
    f[i][3] = rsqrtf(ss3 * 0.125f + 1e-4f) * qm;
  }

  if (g == 2) {
#pragma unroll
    for (int n = 0; n < 8; ++n) {
      unsigned short* dst = (unsigned short*)v_ds +
          (size_t)((b * 8 + n) * 64) * 1024 + s0 + sl4;
#pragma unroll
      for (int i = 0; i < 4; ++i) {
        int d = dg * 4 + i;
        ushort4_t o;
#pragma unroll
        for (int j = 0; j < 4; ++j) o[j] = f2bf(bf2f(raw[n][i][j]) * f[i][j]);
        *(ushort4_t*)(dst + (size_t)d * 1024) = o;
      }
    }
    return;
  }

  unsigned short* dst0 = (unsigned short*)(g ? k_sd : q_sd) + (size_t)(b * 8) * 65536;
#pragma unroll 1
  for (int n = 0; n < 8; ++n) {
#pragma unroll
    for (int i = 0; i < 4; i += 2) {
#pragma unroll
      for (int j = 0; j < 4; ++j) {
        unsigned short lo = f2bf(bf2f(raw[n][i][j]) * f[i][j]);
        unsigned short hi = f2bf(bf2f(raw[n][i + 1][j]) * f[i + 1][j]);
        *(unsigned*)&trans[sl4 + j][dg * 4 + i] = (unsigned)lo | ((unsigned)hi << 16);
      }
    }
    __syncthreads();
    {
      const unsigned short* rs = &trans[t >> 2][(t & 3) * 16];
      uint2 r0 = *(const uint2*)(rs + 0);
      uint2 r1 = *(const uint2*)(rs + 4);
      uint2 r2 = *(const uint2*)(rs + 8);
      uint2 r3 = *(const uint2*)(rs + 12);
      unsigned short* dst = dst0 + (size_t)n * 65536 +
          (size_t)(s0 + (t >> 2)) * 64 + (t & 3) * 16;
      uint4 o0 = {r0.x, r0.y, r1.x, r1.y};
      uint4 o1 = {r2.x, r2.y, r3.x, r3.y};
      *(uint4*)dst = o0;
      *(uint4*)(dst + 8) = o1;
    }
    __syncthreads();
  }
}

// ---------------- flash attention, bf16 MFMA, barrier-free -----------------
// Grid (bn=128 FAST -> XCD-local, qb=8). 4 independent waves (no barriers);
// wave w owns 32 q (2 subtiles). Swapped operands: S^T=mfma(K,Q^T),
// O^T=mfma(V^T,P^T). K/V A-frags are 16B-contiguous in k_sd[s][d] /
// v_ds[d][s] and L2-resident (256KB per bn) -> read DIRECT from global.
// K prefetched one tile ahead (hidden under PV); V issued before softmax.
__global__ __launch_bounds__(256) void attn_mfma(
    const __hip_bfloat16* __restrict__ q_sd, const __hip_bfloat16* __restrict__ k_sd,
    const __hip_bfloat16* __restrict__ v_ds, __hip_bfloat16* __restrict__ y_t) {
  __shared__ __align__(16) unsigned short Ps[4][32][72];  // per-wave P rows
  int t = threadIdx.x;
  int w = t >> 6, l = t & 63;
  int l15 = l & 15, lg = l >> 4;
  int bn = blockIdx.x, qb = blockIdx.y;
  const char* qg = (const char*)(q_sd + (size_t)bn * 65536);   // [s][d]
  const char* kg = (const char*)(k_sd + (size_t)bn * 65536);   // [s][d]
  const char* vg = (const char*)(v_ds + (size_t)bn * 65536);   // [d][s]

  // Q B-fragments in registers for the whole block.
  short8 bq[2][2];
  int qrow_base = qb * 128 + w * 32;
#pragma unroll
  for (int c = 0; c < 2; ++c)
#pragma unroll
    for (int h = 0; h < 2; ++h)
      bq[c][h] = *(const short8*)(qg +
          2 * ((size_t)(qrow_base + c * 16 + l15) * 64 + h * 32 + lg * 8));

  // per-lane base pointers for direct K/V fragment loads
  const char* kp = kg + (size_t)(l15 * 128 + lg * 16);   // +kb*8192 +kt*2048 +h*64
  const char* vp = vg + (size_t)(l15 * 2048 + lg * 16);  // +kb*128 +dt*32768 +h*64

  f32x4 o_acc[4][2];
#pragma unroll
  for (int dt = 0; dt < 4; ++dt)
#pragma unroll
    for (int c = 0; c < 2; ++c) o_acc[dt][c] = (f32x4){0.f, 0.f, 0.f, 0.f};
  float m_run[2] = {-1e30f, -1e30f}, l_run[2] = {0.f, 0.f};

  short8 a_k[4][2];
#pragma unroll
  for (int kt = 0; kt < 4; ++kt)
#pragma unroll
    for (int h = 0; h < 2; ++h)
      a_k[kt][h] = *(const short8*)(kp + kt * 2048 + h * 64);

  for (int kb = 0; kb < 16; ++kb) {
    // ---- S^T = K · Q^T
    f32x4 s_acc[4][2];
    __builtin_amdgcn_s_setprio(1);
#pragma unroll
    for (int kt = 0; kt < 4; ++kt)
#pragma unroll
      for (int c = 0; c < 2; ++c) {
        f32x4 acc = (f32x4){0.f, 0.f, 0.f, 0.f};
        acc = __builtin_amdgcn_mfma_f32_16x16x32_bf16(a_k[kt][0], bq[c][0], acc, 0, 0, 0);
        acc = __builtin_amdgcn_mfma_f32_16x16x32_bf16(a_k[kt][1], bq[c][1], acc, 0, 0, 0);
        s_acc[kt][c] = acc;
      }
    __builtin_amdgcn_s_setprio(0);
    // ---- issue V loads now (consumed after softmax; latency hidden)
    short8 a_v[4][2];
#pragma unroll
    for (int dt = 0; dt < 4; ++dt)
#pragma unroll
      for (int h = 0; h < 2; ++h)
        a_v[dt][h] = *(const short8*)(vp + (size_t)dt * 32768 + kb * 128 + h * 64);
    // ---- online softmax (defer-max, THR=11 log2-units)
#pragma unroll
    for (int c = 0; c < 2; ++c) {
      float mt = -1e30f;
#pragma unroll
      for (int kt = 0; kt < 4; ++kt) {
        f32x4 s4 = s_acc[kt][c];
        mt = fmaxf(mt, fmaxf(fmaxf(s4[0], s4[1]), fmaxf(s4[2], s4[3])));
      }
      mt = fmaxf(mt, __shfl_xor(mt, 16, 64));
      mt = fmaxf(mt, __shfl_xor(mt, 32, 64));
      if (!__all(mt <= m_run[c] + 11.0f)) {
        float m_new = fmaxf(m_run[c], mt);
        float fsc = exp2f(m_run[c] - m_new);
        m_run[c] = m_new;
        l_run[c] *= fsc;
#pragma unroll
        for (int dt = 0; dt < 4; ++dt)
#pragma unroll
          for (int r = 0; r < 4; ++r) o_acc[dt][c][r] *= fsc;
      }
      float mr = m_run[c];
      float ts = 0.f;
#pragma unroll
      for (int kt = 0; kt < 4; ++kt) {
        float p0 = exp2f(s_acc[kt][c][0] - mr);
        float p1 = exp2f(s_acc[kt][c][1] - mr);
        float p2 = exp2f(s_acc[kt][c][2] - mr);
        float p3 = exp2f(s_acc[kt][c][3] - mr);
        ts += (p0 + p1) + (p2 + p3);
        uint2 pr;
        pr.x = cvt_pk(p0, p1);
        pr.y = cvt_pk(p2, p3);
        *(uint2*)&Ps[w][c * 16 + l15][kt * 16 + lg * 4] = pr;
      }
      ts += __shfl_xor(ts, 16, 64);
      ts += __shfl_xor(ts, 32, 64);
      l_run[c] += ts;
    }
    // ---- prefetch next K tile (in flight across PV)
    if (kb < 15) {
#pragma unroll
      for (int kt = 0; kt < 4; ++kt)
#pragma unroll
        for (int h = 0; h < 2; ++h)
          a_k[kt][h] = *(const short8*)(kp + (size_t)(kb + 1) * 8192 + kt * 2048 + h * 64);
    }
    // ---- P fragments from per-wave LDS
    short8 pbf[2][2];
#pragma unroll
    for (int c = 0; c < 2; ++c)
#pragma unroll
      for (int h = 0; h < 2; ++h)
        pbf[c][h] = *(const short8*)((const char*)&Ps[w][c * 16 + l15][0] + (lg * 8 + h * 32) * 2);
    // ---- O^T += V^T · P^T
    __builtin_amdgcn_s_setprio(1);
#pragma unroll
    for (int dt = 0; dt < 4; ++dt)
#pragma unroll
      for (int c = 0; c < 2; ++c) {
        o_acc[dt][c] = __builtin_amdgcn_mfma_f32_16x16x32_bf16(a_v[dt][0], pbf[c][0], o_acc[dt][c], 0, 0, 0);
        o_acc[dt][c] = __builtin_amdgcn_mfma_f32_16x16x32_bf16(a_v[dt][1], pbf[c][1], o_acc[dt][c], 0, 0, 0);
      }
    __builtin_amdgcn_s_setprio(0);
  }
  // ---- epilogue: y_t[b][s=q][ch = n*64+d]
  int b_ = bn >> 3, n_ = bn & 7;
#pragma unroll
  for (int c = 0; c < 2; ++c) {
    float invl = 1.0f / l_run[c];
    int q = qb * 128 + w * 32 + c * 16 + l15;
    __hip_bfloat16* yrow = y_t + (size_t)b_ * 524288 + (size_t)q * 512 + n_ * 64 + lg * 4;
#pragma unroll
    for (int dt = 0; dt < 4; ++dt) {
      uint2 pr;
      pr.x = cvt_pk(o_acc[dt][c][0] * invl, o_acc[dt][c][1] * invl);
      pr.y = cvt_pk(o_acc[dt][c][2] * invl, o_acc[dt][c][3] * invl);
      *(uint2*)(yrow + dt * 16) = pr;
    }
  }
}

// ---------------------------------------------------------------------------
extern "C" void kernel_launch(void* const* d_in, const int* in_sizes, int n_in,
                              void* d_out, int out_size, void* d_ws, size_t ws_size,
                              hipStream_t stream) {
  const float* x      = (const float*)d_in[0];  // [16][512][1024]
  const float* w_attn = (const float*)d_in[1];  // [1536][512]
  const float* w_proj = (const float*)d_in[2];  // [512][512]
  float* out = (float*)d_out;

  // workspace (bf16 elements, ~104 MB total)
  __hip_bfloat16* wn_attn = (__hip_bfloat16*)d_ws;        // 1536*512
  __hip_bfloat16* wn_proj = wn_attn + 786432;             // 512*512
  __hip_bfloat16* x_t     = wn_proj + 262144;             // 16*1024*512
  __hip_bfloat16* v_ds    = x_t;                          // alias (x_t dead after gemm<0>)
  __hip_bfloat16* xp      = x_t + 8388608;                // 16*1536*1024 bf16
  __hip_bfloat16* y_t     = xp;                           // alias (xp dead after norm_pack)
  __hip_bfloat16* q_sd    = xp + 25165824;                // 16*8*1024*64
  __hip_bfloat16* k_sd    = q_sd + 8388608;

  wnorm_kernel<<<dim3(2048), dim3(256), 0, stream>>>(w_attn, w_proj, wn_attn, wn_proj);
  xt_kernel<<<dim3(16, 8, 16), dim3(256), 0, stream>>>(x, x_t);
  gemm_bf16<0><<<dim3(8, 12, 16), dim3(256), 0, stream>>>(wn_attn, x_t, xp, nullptr, 1536);
  norm_pack<<<dim3(16, 3, 16), dim3(256), 0, stream>>>(xp, q_sd, k_sd, v_ds);
  attn_mfma<<<dim3(128, 8), dim3(256), 0, stream>>>(q_sd, k_sd, v_ds, y_t);
  gemm_bf16<1><<<dim3(8, 4, 16), dim3(256), 0, stream>>>(wn_proj, y_t, out, x, 512);
}

// Round 6
// 176.734 us; speedup vs baseline: 1.2300x; 1.2300x over previous
//
#include <hip/hip_runtime.h>
#include <hip/hip_bf16.h>

// ---------------------------------------------------------------------------
// CosineAttention forward.  b=16, c=512, h=w=32 -> seq=1024, heads=8, hd=64.
//
// Pipeline (all matmuls bf16 MFMA 16x16x32, fp32 accumulate):
//  1) wnorm_kernel : normalized bf16 w_attn (1536x512), w_proj (512x512)
//  2) xt_kernel    : x fp32 [b][c][s] -> x_t bf16 [b][s][c]
//  3) gemm_bf16<0> : xp[b][1536][1024] bf16 = wn_attn @ x   (B = x_t)
//  4) norm_pack    : fused pixel_norm + repack: q_sd,k_sd bf16 [bn][s][d]
//                    (Q gets 0.125*log2e), v_ds bf16 [bn][d][s]
//  5) attn_mfma    : flash attention, 8 waves / 256 q per block, K/V LDS
//                    double-buffer, defer-max, cvt_pk, setprio, XCD-local
//                    grid; writes y_t bf16 [b][s][ch]
//  6) gemm_bf16<1> : out = mp_add(x, wn_proj @ y)           (B = y_t)
// ---------------------------------------------------------------------------

typedef __attribute__((ext_vector_type(8))) short short8;
typedef __attribute__((ext_vector_type(4))) float f32x4;
typedef __attribute__((ext_vector_type(4))) unsigned short ushort4_t;

__device__ inline unsigned short f2bf(float v) {
  __hip_bfloat16 h = __float2bfloat16(v);
  return *reinterpret_cast<unsigned short*>(&h);
}
__device__ inline float bf2f(unsigned short u) {
  return __uint_as_float((unsigned)u << 16);
}
__device__ inline unsigned cvt_pk(float lo, float hi) {
  unsigned r;
  asm("v_cvt_pk_bf16_f32 %0, %1, %2" : "=v"(r) : "v"(lo), "v"(hi));
  return r;
}
__device__ inline void gload16(const void* g, void* l) {
  __builtin_amdgcn_global_load_lds(
      (const __attribute__((address_space(1))) unsigned int*)g,
      (__attribute__((address_space(3))) unsigned int*)l, 16, 0, 0);
}

// ---------------- weight normalization (bf16 out) --------------------------
__global__ __launch_bounds__(256) void wnorm_kernel(
    const float* __restrict__ wa, const float* __restrict__ wp,
    __hip_bfloat16* __restrict__ wna, __hip_bfloat16* __restrict__ wnp) {
  int o = blockIdx.x;
  const float* src;
  __hip_bfloat16* dst;
  if (o < 1536) { src = wa + (size_t)o * 512; dst = wna + (size_t)o * 512; }
  else          { src = wp + (size_t)(o - 1536) * 512; dst = wnp + (size_t)(o - 1536) * 512; }
  int tid = threadIdx.x;
  float a = src[tid], b = src[tid + 256];
  float ss = a * a + b * b;
#pragma unroll
  for (int off = 32; off > 0; off >>= 1) ss += __shfl_down(ss, off, 64);
  __shared__ float wsum[4];
  if ((tid & 63) == 0) wsum[tid >> 6] = ss;
  __syncthreads();
  float tot = wsum[0] + wsum[1] + wsum[2] + wsum[3];
  float r = 1.0f / (sqrtf(tot) + 2.2627416997969522e-3f);  // n + EPS*sqrt(512)
  dst[tid] = __float2bfloat16(a * r);
  dst[tid + 256] = __float2bfloat16(b * r);
}

// ---------------- x -> bf16 [b][s][c] transpose ----------------------------
__global__ __launch_bounds__(256) void xt_kernel(
    const float* __restrict__ x, __hip_bfloat16* __restrict__ xt) {
  __shared__ __align__(16) unsigned short trans[64][68];
  int s0 = blockIdx.x * 64, c0 = blockIdx.y * 64, b = blockIdx.z;
  int t = threadIdx.x;
  int sl = t & 63, cg = t >> 6;
  const float* src = x + (size_t)b * 524288 + (size_t)(c0 + cg * 16) * 1024 + s0 + sl;
#pragma unroll
  for (int i = 0; i < 16; i += 2) {
    float v0 = src[(size_t)i * 1024];
    float v1 = src[(size_t)(i + 1) * 1024];
    *(unsigned*)&trans[sl][cg * 16 + i] = (unsigned)f2bf(v0) | ((unsigned)f2bf(v1) << 16);
  }
  __syncthreads();
  int sw = t >> 2, cw = (t & 3) * 16;
  __hip_bfloat16* dst = xt + (size_t)b * 524288 + (size_t)(s0 + sw) * 512 + c0 + cw;
  uint2 r0 = *(uint2*)&trans[sw][cw + 0];
  uint2 r1 = *(uint2*)&trans[sw][cw + 4];
  uint2 r2 = *(uint2*)&trans[sw][cw + 8];
  uint2 r3 = *(uint2*)&trans[sw][cw + 12];
  uint4 o0 = {r0.x, r0.y, r1.x, r1.y};
  uint4 o1 = {r2.x, r2.y, r3.x, r3.y};
  *(uint4*)dst = o0;
  *(uint4*)((char*)dst + 16) = o1;
}

// ---------------- bf16 MFMA GEMM:  Out[b][M][1024] = A[Mx512] @ B[b]^T -----
// MODE 0: Out bf16 (QKV).  MODE 1: Out fp32 = mp_add(resid, acc).
template <int MODE>
__global__ __launch_bounds__(256) void gemm_bf16(
    const __hip_bfloat16* __restrict__ A, const __hip_bfloat16* __restrict__ B,
    void* __restrict__ Outv, const float* __restrict__ resid, int M) {
  __shared__ __align__(16) char Al[2][16384];
  __shared__ __align__(16) char Bl[2][16384];
  int t = threadIdx.x;
  int w = t >> 6, l = t & 63;
  int l15 = l & 15, lg = l >> 4;
  int wm = w >> 1, wn = w & 1;
  int n0 = blockIdx.x * 128, m0 = blockIdx.y * 128, b = blockIdx.z;
  const char* Ab = (const char*)A + (size_t)m0 * 1024;
  const char* Bb = (const char*)B + (size_t)b * 1048576 + (size_t)n0 * 1024;
  int rl = t >> 3;
  int soff = ((t & 7) * 16) ^ ((rl & 7) << 4);
  const char* asrc = Ab + (size_t)rl * 1024 + soff;
  const char* bsrc = Bb + (size_t)rl * 1024 + soff;

#define STAGE(bi, k0b)                                                    \
  do {                                                                    \
    _Pragma("unroll") for (int i = 0; i < 4; ++i) {                       \
      gload16(asrc + (size_t)i * 32768 + (k0b), Al[bi] + i * 4096 + w * 1024); \
      gload16(bsrc + (size_t)i * 32768 + (k0b), Bl[bi] + i * 4096 + w * 1024); \
    }                                                                     \
  } while (0)

  f32x4 acc[4][4];
#pragma unroll
  for (int mi = 0; mi < 4; ++mi)
#pragma unroll
    for (int ni = 0; ni < 4; ++ni) acc[mi][ni] = (f32x4){0.f, 0.f, 0.f, 0.f};

  STAGE(0, 0);
  __syncthreads();

  for (int ks = 0; ks < 8; ++ks) {
    int buf = ks & 1;
    if (ks < 7) STAGE(buf ^ 1, (ks + 1) * 128);
    short8 af[4][2], bf[4][2];
#pragma unroll
    for (int mi = 0; mi < 4; ++mi) {
      int row = wm * 64 + mi * 16 + l15;
      int sw = (row & 7) << 4;
#pragma unroll
      for (int h = 0; h < 2; ++h)
        af[mi][h] = *(const short8*)(Al[buf] + row * 128 + ((h * 64 + lg * 16) ^ sw));
    }
#pragma unroll
    for (int ni = 0; ni < 4; ++ni) {
      int row = wn * 64 + ni * 16 + l15;
      int sw = (row & 7) << 4;
#pragma unroll
      for (int h = 0; h < 2; ++h)
        bf[ni][h] = *(const short8*)(Bl[buf] + row * 128 + ((h * 64 + lg * 16) ^ sw));
    }
    __builtin_amdgcn_s_setprio(1);
#pragma unroll
    for (int mi = 0; mi < 4; ++mi)
#pragma unroll
      for (int ni = 0; ni < 4; ++ni) {
        acc[mi][ni] = __builtin_amdgcn_mfma_f32_16x16x32_bf16(af[mi][0], bf[ni][0], acc[mi][ni], 0, 0, 0);
        acc[mi][ni] = __builtin_amdgcn_mfma_f32_16x16x32_bf16(af[mi][1], bf[ni][1], acc[mi][ni], 0, 0, 0);
      }
    __builtin_amdgcn_s_setprio(0);
    if (ks < 7) __syncthreads();
  }
#undef STAGE

  if (MODE == 0) {
    unsigned short* outb = (unsigned short*)Outv + (size_t)b * M * 1024;
#pragma unroll
    for (int mi = 0; mi < 4; ++mi) {
      int row = m0 + wm * 64 + mi * 16 + lg * 4;
#pragma unroll
      for (int r = 0; r < 4; ++r) {
        unsigned short* orow = outb + (size_t)(row + r) * 1024 + n0 + wn * 64 + l15;
#pragma unroll
        for (int ni = 0; ni < 4; ++ni) orow[ni * 16] = f2bf(acc[mi][ni][r]);
      }
    }
  } else {
    float* outb = (float*)Outv + (size_t)b * M * 1024;
    const float* rb = resid + (size_t)b * M * 1024;
#pragma unroll
    for (int mi = 0; mi < 4; ++mi) {
      int row = m0 + wm * 64 + mi * 16 + lg * 4;
#pragma unroll
      for (int r = 0; r < 4; ++r) {
        float* orow = outb + (size_t)(row + r) * 1024 + n0 + wn * 64 + l15;
        const float* rrow = rb + (size_t)(row + r) * 1024 + n0 + wn * 64 + l15;
#pragma unroll
        for (int ni = 0; ni < 4; ++ni)
          orow[ni * 16] = 0.9191450300180578f * rrow[ni * 16] +
                          0.39391929857916763f * acc[mi][ni][r];
      }
    }
  }
}

// ---------------- fused pixel_norm + repack ---------------------------------
__global__ __launch_bounds__(256) void norm_pack(
    const __hip_bfloat16* __restrict__ xp,
    __hip_bfloat16* __restrict__ q_sd, __hip_bfloat16* __restrict__ k_sd,
    __hip_bfloat16* __restrict__ v_ds) {
  __shared__ __align__(16) unsigned short trans[64][68];
  int s0 = blockIdx.x * 64, g = blockIdx.y, b = blockIdx.z;
  int t = threadIdx.x;
  int s16 = t & 15, dg = t >> 4;
  int sl4 = s16 * 4;
  const unsigned short* src = (const unsigned short*)xp +
      (size_t)(b * 1536 + g * 512) * 1024 + s0 + sl4;
  float qm = (g == 0) ? 0.18033688011112042f : 1.0f;  // 0.125*log2(e) in Q

  ushort4_t raw[8][4];
  float f[4][4];
#pragma unroll
  for (int i = 0; i < 4; ++i) {
    int d = dg * 4 + i;
    float ss0 = 0.f, ss1 = 0.f, ss2 = 0.f, ss3 = 0.f;
#pragma unroll
    for (int n = 0; n < 8; ++n) {
      ushort4_t pk = *(const ushort4_t*)(src + (size_t)(n * 64 + d) * 1024);
      raw[n][i] = pk;
      float v0 = bf2f(pk[0]), v1 = bf2f(pk[1]), v2 = bf2f(pk[2]), v3 = bf2f(pk[3]);
      ss0 += v0 * v0; ss1 += v1 * v1; ss2 += v2 * v2; ss3 += v3 * v3;
    }
    f[i][0] = rsqrtf(ss0 * 0.125f + 1e-4f) * qm;
    f[i][1] = rsqrtf(ss1 * 0.125f + 1e-4f) * qm;
    f[i][2] = rsqrtf(ss2 * 0.125f + 1e-4f) * qm;
    f[i][3] = rsqrtf(ss3 * 0.125f + 1e-4f) * qm;
  }

  if (g == 2) {
#pragma unroll
    for (int n = 0; n < 8; ++n) {
      unsigned short* dst = (unsigned short*)v_ds +
          (size_t)((b * 8 + n) * 64) * 1024 + s0 + sl4;
#pragma unroll
      for (int i = 0; i < 4; ++i) {
        int d = dg * 4 + i;
        ushort4_t o;
#pragma unroll
        for (int j = 0; j < 4; ++j) o[j] = f2bf(bf2f(raw[n][i][j]) * f[i][j]);
        *(ushort4_t*)(dst + (size_t)d * 1024) = o;
      }
    }
    return;
  }

  unsigned short* dst0 = (unsigned short*)(g ? k_sd : q_sd) + (size_t)(b * 8) * 65536;
#pragma unroll 1
  for (int n = 0; n < 8; ++n) {
#pragma unroll
    for (int i = 0; i < 4; i += 2) {
#pragma unroll
      for (int j = 0; j < 4; ++j) {
        unsigned short lo = f2bf(bf2f(raw[n][i][j]) * f[i][j]);
        unsigned short hi = f2bf(bf2f(raw[n][i + 1][j]) * f[i + 1][j]);
        *(unsigned*)&trans[sl4 + j][dg * 4 + i] = (unsigned)lo | ((unsigned)hi << 16);
      }
    }
    __syncthreads();
    {
      const unsigned short* rs = &trans[t >> 2][(t & 3) * 16];
      uint2 r0 = *(const uint2*)(rs + 0);
      uint2 r1 = *(const uint2*)(rs + 4);
      uint2 r2 = *(const uint2*)(rs + 8);
      uint2 r3 = *(const uint2*)(rs + 12);
      unsigned short* dst = dst0 + (size_t)n * 65536 +
          (size_t)(s0 + (t >> 2)) * 64 + (t & 3) * 16;
      uint4 o0 = {r0.x, r0.y, r1.x, r1.y};
      uint4 o1 = {r2.x, r2.y, r3.x, r3.y};
      *(uint4*)dst = o0;
      *(uint4*)(dst + 8) = o1;
    }
    __syncthreads();
  }
}

// ---------------- flash attention, bf16 MFMA -------------------------------
// Grid (bn=128 FAST -> XCD-local, qb=4). 8 waves / 512 threads; wave w owns
// 32 q (2 subtiles); block covers 256 q. K/V double-buffered in LDS with
// XOR swizzle (write==read). 512 blocks, 69.6KB LDS -> 2 blocks/CU, fully
// resident. Swapped operands: S^T=mfma(K,Q^T), O^T=mfma(V^T,P^T).
__global__ __launch_bounds__(512) void attn_mfma(
    const __hip_bfloat16* __restrict__ q_sd, const __hip_bfloat16* __restrict__ k_sd,
    const __hip_bfloat16* __restrict__ v_ds, __hip_bfloat16* __restrict__ y_t) {
  __shared__ __align__(16) char K_lds[2][8192];
  __shared__ __align__(16) char V_lds[2][8192];
  __shared__ __align__(16) unsigned short Ps[8][32][72];  // per-wave P rows
  int t = threadIdx.x;
  int w = t >> 6, l = t & 63;
  int l15 = l & 15, lg = l >> 4;
  int bn = blockIdx.x, qb = blockIdx.y;
  const char* qg = (const char*)(q_sd + (size_t)bn * 65536);   // [s][d]
  const char* kg = (const char*)(k_sd + (size_t)bn * 65536);   // [s][d]
  const char* vg = (const char*)(v_ds + (size_t)bn * 65536);   // [d][s]

  // Q B-fragments in registers for the whole block.
  short8 bq[2][2];
  int qrow_base = qb * 256 + w * 32;
#pragma unroll
  for (int c = 0; c < 2; ++c)
#pragma unroll
    for (int h = 0; h < 2; ++h)
      bq[c][h] = *(const short8*)(qg +
          2 * ((size_t)(qrow_base + c * 16 + l15) * 64 + h * 32 + lg * 8));

  f32x4 o_acc[4][2];
#pragma unroll
  for (int dt = 0; dt < 4; ++dt)
#pragma unroll
    for (int c = 0; c < 2; ++c) o_acc[dt][c] = (f32x4){0.f, 0.f, 0.f, 0.f};
  float m_run[2] = {-1e30f, -1e30f}, l_run[2] = {0.f, 0.f};

  // staging: 512 threads x 16B = one 8KB tile each for K and V
  int rowS = t >> 3;               // 0..63
  int offS = (t & 7) * 16;         // 0..112
  int swrS = (rowS & 7) << 4;
  {
    uint4 a = *(const uint4*)(kg + (size_t)t * 16);
    uint4 b2 = *(const uint4*)(vg + (size_t)rowS * 2048 + offS);
    *(uint4*)(K_lds[0] + ((t * 16) ^ swrS)) = a;
    *(uint4*)(V_lds[0] + ((t * 16) ^ swrS)) = b2;
  }
  __syncthreads();

  for (int kb = 0; kb < 16; ++kb) {
    int buf = kb & 1;
    uint4 pk, pv;
    if (kb < 15) {  // issue next-tile loads early (hide HBM/L2 under compute)
      pk = *(const uint4*)(kg + (size_t)(kb + 1) * 8192 + (size_t)t * 16);
      pv = *(const uint4*)(vg + (size_t)rowS * 2048 + (size_t)(kb + 1) * 128 + offS);
    }
    // ---- S^T = K · Q^T
    short8 a_k[4][2];
#pragma unroll
    for (int kt = 0; kt < 4; ++kt) {
      int key = kt * 16 + l15;
      int sw = (key & 7) << 4;
#pragma unroll
      for (int h = 0; h < 2; ++h)
        a_k[kt][h] = *(const short8*)(K_lds[buf] + ((key * 128 + h * 64 + lg * 16) ^ sw));
    }
    f32x4 s_acc[4][2];
    __builtin_amdgcn_s_setprio(1);
#pragma unroll
    for (int kt = 0; kt < 4; ++kt)
#pragma unroll
      for (int c = 0; c < 2; ++c) {
        f32x4 acc = (f32x4){0.f, 0.f, 0.f, 0.f};
        acc = __builtin_amdgcn_mfma_f32_16x16x32_bf16(a_k[kt][0], bq[c][0], acc, 0, 0, 0);
        acc = __builtin_amdgcn_mfma_f32_16x16x32_bf16(a_k[kt][1], bq[c][1], acc, 0, 0, 0);
        s_acc[kt][c] = acc;
      }
    __builtin_amdgcn_s_setprio(0);
    // ---- online softmax (defer-max, THR=11 log2-units)
#pragma unroll
    for (int c = 0; c < 2; ++c) {
      float mt = -1e30f;
#pragma unroll
      for (int kt = 0; kt < 4; ++kt) {
        f32x4 s4 = s_acc[kt][c];
        mt = fmaxf(mt, fmaxf(fmaxf(s4[0], s4[1]), fmaxf(s4[2], s4[3])));
      }
      mt = fmaxf(mt, __shfl_xor(mt, 16, 64));
      mt = fmaxf(mt, __shfl_xor(mt, 32, 64));
      if (!__all(mt <= m_run[c] + 11.0f)) {
        float m_new = fmaxf(m_run[c], mt);
        float fsc = exp2f(m_run[c] - m_new);
        m_run[c] = m_new;
        l_run[c] *= fsc;
#pragma unroll
        for (int dt = 0; dt < 4; ++dt)
#pragma unroll
          for (int r = 0; r < 4; ++r) o_acc[dt][c][r] *= fsc;
      }
      float mr = m_run[c];
      float ts = 0.f;
#pragma unroll
      for (int kt = 0; kt < 4; ++kt) {
        float p0 = exp2f(s_acc[kt][c][0] - mr);
        float p1 = exp2f(s_acc[kt][c][1] - mr);
        float p2 = exp2f(s_acc[kt][c][2] - mr);
        float p3 = exp2f(s_acc[kt][c][3] - mr);
        ts += (p0 + p1) + (p2 + p3);
        uint2 pr;
        pr.x = cvt_pk(p0, p1);
        pr.y = cvt_pk(p2, p3);
        *(uint2*)&Ps[w][c * 16 + l15][kt * 16 + lg * 4] = pr;
      }
      ts += __shfl_xor(ts, 16, 64);
      ts += __shfl_xor(ts, 32, 64);
      l_run[c] += ts;
    }
    // ---- V fragments + P fragments
    short8 a_v[4][2];
#pragma unroll
    for (int dt = 0; dt < 4; ++dt) {
      int d = dt * 16 + l15;
      int sw = (d & 7) << 4;
#pragma unroll
      for (int h = 0; h < 2; ++h)
        a_v[dt][h] = *(const short8*)(V_lds[buf] + ((d * 128 + h * 64 + lg * 16) ^ sw));
    }
    short8 pbf[2][2];
#pragma unroll
    for (int c = 0; c < 2; ++c)
#pragma unroll
      for (int h = 0; h < 2; ++h)
        pbf[c][h] = *(const short8*)((const char*)&Ps[w][c * 16 + l15][0] + (lg * 8 + h * 32) * 2);
    // ---- O^T += V^T · P^T
    __builtin_amdgcn_s_setprio(1);
#pragma unroll
    for (int dt = 0; dt < 4; ++dt)
#pragma unroll
      for (int c = 0; c < 2; ++c) {
        o_acc[dt][c] = __builtin_amdgcn_mfma_f32_16x16x32_bf16(a_v[dt][0], pbf[c][0], o_acc[dt][c], 0, 0, 0);
        o_acc[dt][c] = __builtin_amdgcn_mfma_f32_16x16x32_bf16(a_v[dt][1], pbf[c][1], o_acc[dt][c], 0, 0, 0);
      }
    __builtin_amdgcn_s_setprio(0);
    // ---- write next tile into the other buffer, single barrier
    if (kb < 15) {
      int nb = buf ^ 1;
      *(uint4*)(K_lds[nb] + ((t * 16) ^ swrS)) = pk;
      *(uint4*)(V_lds[nb] + ((t * 16) ^ swrS)) = pv;
    }
    __syncthreads();
  }
  // ---- epilogue: y_t[b][s=q][ch = n*64+d]
  int b_ = bn >> 3, n_ = bn & 7;
#pragma unroll
  for (int c = 0; c < 2; ++c) {
    float invl = 1.0f / l_run[c];
    int q = qb * 256 + w * 32 + c * 16 + l15;
    __hip_bfloat16* yrow = y_t + (size_t)b_ * 524288 + (size_t)q * 512 + n_ * 64 + lg * 4;
#pragma unroll
    for (int dt = 0; dt < 4; ++dt) {
      uint2 pr;
      pr.x = cvt_pk(o_acc[dt][c][0] * invl, o_acc[dt][c][1] * invl);
      pr.y = cvt_pk(o_acc[dt][c][2] * invl, o_acc[dt][c][3] * invl);
      *(uint2*)(yrow + dt * 16) = pr;
    }
  }
}

// ---------------------------------------------------------------------------
extern "C" void kernel_launch(void* const* d_in, const int* in_sizes, int n_in,
                              void* d_out, int out_size, void* d_ws, size_t ws_size,
                              hipStream_t stream) {
  const float* x      = (const float*)d_in[0];  // [16][512][1024]
  const float* w_attn = (const float*)d_in[1];  // [1536][512]
  const float* w_proj = (const float*)d_in[2];  // [512][512]
  float* out = (float*)d_out;

  // workspace (bf16 elements, ~104 MB total)
  __hip_bfloat16* wn_attn = (__hip_bfloat16*)d_ws;        // 1536*512
  __hip_bfloat16* wn_proj = wn_attn + 786432;             // 512*512
  __hip_bfloat16* x_t     = wn_proj + 262144;             // 16*1024*512
  __hip_bfloat16* v_ds    = x_t;                          // alias (x_t dead after gemm<0>)
  __hip_bfloat16* xp      = x_t + 8388608;                // 16*1536*1024 bf16
  __hip_bfloat16* y_t     = xp;                           // alias (xp dead after norm_pack)
  __hip_bfloat16* q_sd    = xp + 25165824;                // 16*8*1024*64
  __hip_bfloat16* k_sd    = q_sd + 8388608;

  wnorm_kernel<<<dim3(2048), dim3(256), 0, stream>>>(w_attn, w_proj, wn_attn, wn_proj);
  xt_kernel<<<dim3(16, 8, 16), dim3(256), 0, stream>>>(x, x_t);
  gemm_bf16<0><<<dim3(8, 12, 16), dim3(256), 0, stream>>>(wn_attn, x_t, xp, nullptr, 1536);
  norm_pack<<<dim3(16, 3, 16), dim3(256), 0, stream>>>(xp, q_sd, k_sd, v_ds);
  attn_mfma<<<dim3(128, 4), dim3(512), 0, stream>>>(q_sd, k_sd, v_ds, y_t);
  gemm_bf16<1><<<dim3(8, 4, 16), dim3(256), 0, stream>>>(wn_proj, y_t, out, x, 512);
}

// Round 9
// 162.954 us; speedup vs baseline: 1.3340x; 1.0846x over previous
//
#include <hip/hip_runtime.h>
#include <hip/hip_bf16.h>

// ---------------------------------------------------------------------------
// CosineAttention forward.  b=16, c=512, h=w=32 -> seq=1024, heads=8, hd=64.
//
// Pipeline (matmuls bf16 MFMA, fp32 accumulate):
//  1) wnorm_kernel : normalized bf16 w_attn (1536x512), w_proj (512x512)
//  2) xt_kernel    : x fp32 [b][c][s] -> x_t bf16 [b][s][c]
//  3) gemm_bf16<0> : xp[b][1536][1024] bf16 = wn_attn @ x   (B = x_t)
//  4) norm_pack    : fused pixel_norm + repack: q_sd,k_sd bf16 [bn][s][d]
//                    (Q gets 0.125*log2e), v_ds bf16 [bn][d][s]
//  5) attn_mfma    : flash attention, 32x32x16 MFMA, P fully in-register via
//                    KEY-PERMUTED QK^T (pi swaps key bits 2<->3 so the PV
//                    B-frag is lane-local; no exchange, no P LDS), K/V LDS
//                    dbuf, defer-max, setprio, XCD-local grid; y_t [b][s][ch]
//  6) gemm_bf16<1> : out = mp_add(x, wn_proj @ y)           (B = y_t)
// ---------------------------------------------------------------------------

typedef __attribute__((ext_vector_type(8))) short short8;
typedef __attribute__((ext_vector_type(4))) float f32x4;
typedef __attribute__((ext_vector_type(16))) float f32x16;
typedef __attribute__((ext_vector_type(4))) unsigned short ushort4_t;
typedef __attribute__((ext_vector_type(4))) unsigned int uint4_t;

__device__ inline unsigned short f2bf(float v) {
  __hip_bfloat16 h = __float2bfloat16(v);
  return *reinterpret_cast<unsigned short*>(&h);
}
__device__ inline float bf2f(unsigned short u) {
  return __uint_as_float((unsigned)u << 16);
}
__device__ inline unsigned cvt_pk(float lo, float hi) {
  unsigned r;
  asm("v_cvt_pk_bf16_f32 %0, %1, %2" : "=v"(r) : "v"(lo), "v"(hi));
  return r;
}
__device__ inline void gload16(const void* g, void* l) {
  __builtin_amdgcn_global_load_lds(
      (const __attribute__((address_space(1))) unsigned int*)g,
      (__attribute__((address_space(3))) unsigned int*)l, 16, 0, 0);
}

// ---------------- weight normalization (bf16 out) --------------------------
__global__ __launch_bounds__(256) void wnorm_kernel(
    const float* __restrict__ wa, const float* __restrict__ wp,
    __hip_bfloat16* __restrict__ wna, __hip_bfloat16* __restrict__ wnp) {
  int o = blockIdx.x;
  const float* src;
  __hip_bfloat16* dst;
  if (o < 1536) { src = wa + (size_t)o * 512; dst = wna + (size_t)o * 512; }
  else          { src = wp + (size_t)(o - 1536) * 512; dst = wnp + (size_t)(o - 1536) * 512; }
  int tid = threadIdx.x;
  float a = src[tid], b = src[tid + 256];
  float ss = a * a + b * b;
#pragma unroll
  for (int off = 32; off > 0; off >>= 1) ss += __shfl_down(ss, off, 64);
  __shared__ float wsum[4];
  if ((tid & 63) == 0) wsum[tid >> 6] = ss;
  __syncthreads();
  float tot = wsum[0] + wsum[1] + wsum[2] + wsum[3];
  float r = 1.0f / (sqrtf(tot) + 2.2627416997969522e-3f);  // n + EPS*sqrt(512)
  dst[tid] = __float2bfloat16(a * r);
  dst[tid + 256] = __float2bfloat16(b * r);
}

// ---------------- x -> bf16 [b][s][c] transpose ----------------------------
__global__ __launch_bounds__(256) void xt_kernel(
    const float* __restrict__ x, __hip_bfloat16* __restrict__ xt) {
  __shared__ __align__(16) unsigned short trans[64][68];
  int s0 = blockIdx.x * 64, c0 = blockIdx.y * 64, b = blockIdx.z;
  int t = threadIdx.x;
  int sl = t & 63, cg = t >> 6;
  const float* src = x + (size_t)b * 524288 + (size_t)(c0 + cg * 16) * 1024 + s0 + sl;
#pragma unroll
  for (int i = 0; i < 16; i += 2) {
    float v0 = src[(size_t)i * 1024];
    float v1 = src[(size_t)(i + 1) * 1024];
    *(unsigned*)&trans[sl][cg * 16 + i] = (unsigned)f2bf(v0) | ((unsigned)f2bf(v1) << 16);
  }
  __syncthreads();
  int sw = t >> 2, cw = (t & 3) * 16;
  __hip_bfloat16* dst = xt + (size_t)b * 524288 + (size_t)(s0 + sw) * 512 + c0 + cw;
  uint2 r0 = *(uint2*)&trans[sw][cw + 0];
  uint2 r1 = *(uint2*)&trans[sw][cw + 4];
  uint2 r2 = *(uint2*)&trans[sw][cw + 8];
  uint2 r3 = *(uint2*)&trans[sw][cw + 12];
  uint4 o0 = {r0.x, r0.y, r1.x, r1.y};
  uint4 o1 = {r2.x, r2.y, r3.x, r3.y};
  *(uint4*)dst = o0;
  *(uint4*)((char*)dst + 16) = o1;
}

// ---------------- bf16 MFMA GEMM:  Out[b][M][1024] = A[Mx512] @ B[b]^T -----
// MODE 0: Out bf16 (QKV).  MODE 1: Out fp32 = mp_add(resid, acc).
template <int MODE>
__global__ __launch_bounds__(256) void gemm_bf16(
    const __hip_bfloat16* __restrict__ A, const __hip_bfloat16* __restrict__ B,
    void* __restrict__ Outv, const float* __restrict__ resid, int M) {
  __shared__ __align__(16) char Al[2][16384];
  __shared__ __align__(16) char Bl[2][16384];
  int t = threadIdx.x;
  int w = t >> 6, l = t & 63;
  int l15 = l & 15, lg = l >> 4;
  int wm = w >> 1, wn = w & 1;
  int n0 = blockIdx.x * 128, m0 = blockIdx.y * 128, b = blockIdx.z;
  const char* Ab = (const char*)A + (size_t)m0 * 1024;
  const char* Bb = (const char*)B + (size_t)b * 1048576 + (size_t)n0 * 1024;
  int rl = t >> 3;
  int soff = ((t & 7) * 16) ^ ((rl & 7) << 4);
  const char* asrc = Ab + (size_t)rl * 1024 + soff;
  const char* bsrc = Bb + (size_t)rl * 1024 + soff;

#define STAGE(bi, k0b)                                                    \
  do {                                                                    \
    _Pragma("unroll") for (int i = 0; i < 4; ++i) {                       \
      gload16(asrc + (size_t)i * 32768 + (k0b), Al[bi] + i * 4096 + w * 1024); \
      gload16(bsrc + (size_t)i * 32768 + (k0b), Bl[bi] + i * 4096 + w * 1024); \
    }                                                                     \
  } while (0)

  f32x4 acc[4][4];
#pragma unroll
  for (int mi = 0; mi < 4; ++mi)
#pragma unroll
    for (int ni = 0; ni < 4; ++ni) acc[mi][ni] = (f32x4){0.f, 0.f, 0.f, 0.f};

  STAGE(0, 0);
  __syncthreads();

  for (int ks = 0; ks < 8; ++ks) {
    int buf = ks & 1;
    if (ks < 7) STAGE(buf ^ 1, (ks + 1) * 128);
    short8 af[4][2], bf[4][2];
#pragma unroll
    for (int mi = 0; mi < 4; ++mi) {
      int row = wm * 64 + mi * 16 + l15;
      int sw = (row & 7) << 4;
#pragma unroll
      for (int h = 0; h < 2; ++h)
        af[mi][h] = *(const short8*)(Al[buf] + row * 128 + ((h * 64 + lg * 16) ^ sw));
    }
#pragma unroll
    for (int ni = 0; ni < 4; ++ni) {
      int row = wn * 64 + ni * 16 + l15;
      int sw = (row & 7) << 4;
#pragma unroll
      for (int h = 0; h < 2; ++h)
        bf[ni][h] = *(const short8*)(Bl[buf] + row * 128 + ((h * 64 + lg * 16) ^ sw));
    }
    __builtin_amdgcn_s_setprio(1);
#pragma unroll
    for (int mi = 0; mi < 4; ++mi)
#pragma unroll
      for (int ni = 0; ni < 4; ++ni) {
        acc[mi][ni] = __builtin_amdgcn_mfma_f32_16x16x32_bf16(af[mi][0], bf[ni][0], acc[mi][ni], 0, 0, 0);
        acc[mi][ni] = __builtin_amdgcn_mfma_f32_16x16x32_bf16(af[mi][1], bf[ni][1], acc[mi][ni], 0, 0, 0);
      }
    __builtin_amdgcn_s_setprio(0);
    if (ks < 7) __syncthreads();
  }
#undef STAGE

  if (MODE == 0) {
    unsigned short* outb = (unsigned short*)Outv + (size_t)b * M * 1024;
#pragma unroll
    for (int mi = 0; mi < 4; ++mi) {
      int row = m0 + wm * 64 + mi * 16 + lg * 4;
#pragma unroll
      for (int r = 0; r < 4; ++r) {
        unsigned short* orow = outb + (size_t)(row + r) * 1024 + n0 + wn * 64 + l15;
#pragma unroll
        for (int ni = 0; ni < 4; ++ni) orow[ni * 16] = f2bf(acc[mi][ni][r]);
      }
    }
  } else {
    float* outb = (float*)Outv + (size_t)b * M * 1024;
    const float* rb = resid + (size_t)b * M * 1024;
#pragma unroll
    for (int mi = 0; mi < 4; ++mi) {
      int row = m0 + wm * 64 + mi * 16 + lg * 4;
#pragma unroll
      for (int r = 0; r < 4; ++r) {
        float* orow = outb + (size_t)(row + r) * 1024 + n0 + wn * 64 + l15;
        const float* rrow = rb + (size_t)(row + r) * 1024 + n0 + wn * 64 + l15;
#pragma unroll
        for (int ni = 0; ni < 4; ++ni)
          orow[ni * 16] = 0.9191450300180578f * rrow[ni * 16] +
                          0.39391929857916763f * acc[mi][ni][r];
      }
    }
  }
}

// ---------------- fused pixel_norm + repack ---------------------------------
__global__ __launch_bounds__(256) void norm_pack(
    const __hip_bfloat16* __restrict__ xp,
    __hip_bfloat16* __restrict__ q_sd, __hip_bfloat16* __restrict__ k_sd,
    __hip_bfloat16* __restrict__ v_ds) {
  __shared__ __align__(16) unsigned short trans[64][68];
  int s0 = blockIdx.x * 64, g = blockIdx.y, b = blockIdx.z;
  int t = threadIdx.x;
  int s16 = t & 15, dg = t >> 4;
  int sl4 = s16 * 4;
  const unsigned short* src = (const unsigned short*)xp +
      (size_t)(b * 1536 + g * 512) * 1024 + s0 + sl4;
  float qm = (g == 0) ? 0.18033688011112042f : 1.0f;  // 0.125*log2(e) in Q

  ushort4_t raw[8][4];
  float f[4][4];
#pragma unroll
  for (int i = 0; i < 4; ++i) {
    int d = dg * 4 + i;
    float ss0 = 0.f, ss1 = 0.f, ss2 = 0.f, ss3 = 0.f;
#pragma unroll
    for (int n = 0; n < 8; ++n) {
      ushort4_t pk = *(const ushort4_t*)(src + (size_t)(n * 64 + d) * 1024);
      raw[n][i] = pk;
      float v0 = bf2f(pk[0]), v1 = bf2f(pk[1]), v2 = bf2f(pk[2]), v3 = bf2f(pk[3]);
      ss0 += v0 * v0; ss1 += v1 * v1; ss2 += v2 * v2; ss3 += v3 * v3;
    }
    f[i][0] = rsqrtf(ss0 * 0.125f + 1e-4f) * qm;
    f[i][1] = rsqrtf(ss1 * 0.125f + 1e-4f) * qm;
    f[i][2] = rsqrtf(ss2 * 0.125f + 1e-4f) * qm;
    f[i][3] = rsqrtf(ss3 * 0.125f + 1e-4f) * qm;
  }

  if (g == 2) {
#pragma unroll
    for (int n = 0; n < 8; ++n) {
      unsigned short* dst = (unsigned short*)v_ds +
          (size_t)((b * 8 + n) * 64) * 1024 + s0 + sl4;
#pragma unroll
      for (int i = 0; i < 4; ++i) {
        int d = dg * 4 + i;
        ushort4_t o;
#pragma unroll
        for (int j = 0; j < 4; ++j) o[j] = f2bf(bf2f(raw[n][i][j]) * f[i][j]);
        *(ushort4_t*)(dst + (size_t)d * 1024) = o;
      }
    }
    return;
  }

  unsigned short* dst0 = (unsigned short*)(g ? k_sd : q_sd) + (size_t)(b * 8) * 65536;
#pragma unroll 1
  for (int n = 0; n < 8; ++n) {
#pragma unroll
    for (int i = 0; i < 4; i += 2) {
#pragma unroll
      for (int j = 0; j < 4; ++j) {
        unsigned short lo = f2bf(bf2f(raw[n][i][j]) * f[i][j]);
        unsigned short hi = f2bf(bf2f(raw[n][i + 1][j]) * f[i + 1][j]);
        *(unsigned*)&trans[sl4 + j][dg * 4 + i] = (unsigned)lo | ((unsigned)hi << 16);
      }
    }
    __syncthreads();
    {
      const unsigned short* rs = &trans[t >> 2][(t & 3) * 16];
      uint2 r0 = *(const uint2*)(rs + 0);
      uint2 r1 = *(const uint2*)(rs + 4);
      uint2 r2 = *(const uint2*)(rs + 8);
      uint2 r3 = *(const uint2*)(rs + 12);
      unsigned short* dst = dst0 + (size_t)n * 65536 +
          (size_t)(s0 + (t >> 2)) * 64 + (t & 3) * 16;
      uint4 o0 = {r0.x, r0.y, r1.x, r1.y};
      uint4 o1 = {r2.x, r2.y, r3.x, r3.y};
      *(uint4*)dst = o0;
      *(uint4*)(dst + 8) = o1;
    }
    __syncthreads();
  }
}

// ---------------- flash attention, 32x32x16 MFMA, in-register P ------------
// Grid (bn=128 FAST -> XCD-local, qb=4). 8 waves/512 thr; wave w owns 32 q
// (q = qb*256 + w*32 + l31). Swapped operands: S'^T = mfma(K[pi(row)], Q^T),
// where pi swaps key bits 2<->3.  With the verified 32x32 C-layout
// (col=l31, row=(r&3)+8(r>>2)+4h5), pi makes the PV B-frag LANE-LOCAL:
// elem e of kstep j = own reg (e + 8*(j&1)) -> pb[j] = {W[4(j&1)..+3]}.
// Softmax reductions via __shfl_xor(...,32). No P LDS, no permlane.
// K/V double-buffered in LDS, XOR swizzle (write==read).
__global__ __launch_bounds__(512, 4) void attn_mfma(
    const __hip_bfloat16* __restrict__ q_sd, const __hip_bfloat16* __restrict__ k_sd,
    const __hip_bfloat16* __restrict__ v_ds, __hip_bfloat16* __restrict__ y_t) {
  __shared__ __align__(16) char K_lds[2][8192];
  __shared__ __align__(16) char V_lds[2][8192];
  int t = threadIdx.x;
  int w = t >> 6, l = t & 63;
  int l31 = l & 31, h5 = l >> 5;
  int swV = (l31 & 7) << 4;                       // V frag read swizzle
  int pl = (l31 & 0x13) | ((l31 & 4) << 1) | ((l31 & 8) >> 1);  // swap bits 2,3
  int swK = (pl & 7) << 4;                        // K frag read swizzle (pi row)
  int bn = blockIdx.x, qb = blockIdx.y;
  const char* qg = (const char*)(q_sd + (size_t)bn * 65536);   // [s][d]
  const char* kg = (const char*)(k_sd + (size_t)bn * 65536);   // [s][d]
  const char* vg = (const char*)(v_ds + (size_t)bn * 65536);   // [d][s]

  // Q B-frags (32x32x16): col=q=l31, k = h5*8+e within 16-d kstep j
  int q = qb * 256 + w * 32 + l31;
  short8 bq[4];
#pragma unroll
  for (int j = 0; j < 4; ++j)
    bq[j] = *(const short8*)(qg + (size_t)q * 128 + j * 32 + h5 * 16);

  f32x16 o_acc[2];
#pragma unroll
  for (int r = 0; r < 16; ++r) { o_acc[0][r] = 0.f; o_acc[1][r] = 0.f; }
  float m_run = -1e30f, l_run = 0.f;

  // staging: 512 threads x 16B = one 8KB tile each for K and V
  int rowS = t >> 3;
  int offS = (t & 7) * 16;
  int swrS = (rowS & 7) << 4;
  {
    uint4 a = *(const uint4*)(kg + (size_t)t * 16);
    uint4 b2 = *(const uint4*)(vg + (size_t)rowS * 2048 + offS);
    *(uint4*)(K_lds[0] + ((t * 16) ^ swrS)) = a;
    *(uint4*)(V_lds[0] + ((t * 16) ^ swrS)) = b2;
  }
  __syncthreads();

  for (int kb = 0; kb < 16; ++kb) {
    int buf = kb & 1;
    uint4 pk, pv;
    if (kb < 15) {  // prefetch next tile (in flight across softmax+PV)
      pk = *(const uint4*)(kg + (size_t)(kb + 1) * 8192 + (size_t)t * 16);
      pv = *(const uint4*)(vg + (size_t)rowS * 2048 + (size_t)(kb + 1) * 128 + offS);
    }
    // ---- K A-frags with pi-permuted rows: row = 32kt + pl
    short8 a_k[2][4];
#pragma unroll
    for (int kt = 0; kt < 2; ++kt)
#pragma unroll
      for (int j = 0; j < 4; ++j)
        a_k[kt][j] = *(const short8*)(K_lds[buf] +
            (((kt * 32 + pl) * 128 + j * 32 + h5 * 16) ^ swK));
    // ---- S'^T = K_pi · Q^T
    f32x16 s0, s1;
#pragma unroll
    for (int r = 0; r < 16; ++r) { s0[r] = 0.f; s1[r] = 0.f; }
    __builtin_amdgcn_s_setprio(1);
#pragma unroll
    for (int j = 0; j < 4; ++j) {
      s0 = __builtin_amdgcn_mfma_f32_32x32x16_bf16(a_k[0][j], bq[j], s0, 0, 0, 0);
      s1 = __builtin_amdgcn_mfma_f32_32x32x16_bf16(a_k[1][j], bq[j], s1, 0, 0, 0);
    }
    __builtin_amdgcn_s_setprio(0);
    // ---- row max (tree) + cross-half (shfl_xor 32)
    float mx[8];
#pragma unroll
    for (int r = 0; r < 8; ++r)
      mx[r] = fmaxf(fmaxf(s0[r], s0[r + 8]), fmaxf(s1[r], s1[r + 8]));
#pragma unroll
    for (int off = 4; off > 0; off >>= 1)
#pragma unroll
      for (int r = 0; r < off; ++r) mx[r] = fmaxf(mx[r], mx[r + off]);
    float mt = fmaxf(mx[0], __shfl_xor(mx[0], 32, 64));
    // ---- defer-max: rescale only when max grew by >11 (log2 units)
    if (!__all(mt <= m_run + 11.0f)) {
      float m_new = fmaxf(m_run, mt);
      float fsc = exp2f(m_run - m_new);
      m_run = m_new;
      l_run *= fsc;
#pragma unroll
      for (int r = 0; r < 16; ++r) { o_acc[0][r] *= fsc; o_acc[1][r] *= fsc; }
    }
    // ---- P = exp2(S' - m), packed bf16 pairs (consecutive regs)
    unsigned W0[8], W1[8];
    float ts = 0.f;
#pragma unroll
    for (int m = 0; m < 8; ++m) {
      float p0 = exp2f(s0[2 * m] - m_run), p1 = exp2f(s0[2 * m + 1] - m_run);
      float p2 = exp2f(s1[2 * m] - m_run), p3 = exp2f(s1[2 * m + 1] - m_run);
      ts += (p0 + p1) + (p2 + p3);
      W0[m] = cvt_pk(p0, p1);
      W1[m] = cvt_pk(p2, p3);
    }
    l_run += ts + __shfl_xor(ts, 32, 64);
    // ---- PV B-frags are lane-local thanks to pi: pb[j] = W[4(j&1)..+3]
    short8 pb[4];
#pragma unroll
    for (int j = 0; j < 4; ++j) {
      uint4_t pw;
      if (j == 0)      pw = (uint4_t){W0[0], W0[1], W0[2], W0[3]};
      else if (j == 1) pw = (uint4_t){W0[4], W0[5], W0[6], W0[7]};
      else if (j == 2) pw = (uint4_t){W1[0], W1[1], W1[2], W1[3]};
      else             pw = (uint4_t){W1[4], W1[5], W1[6], W1[7]};
      pb[j] = __builtin_bit_cast(short8, pw);
    }
    // ---- V A-frags: row=d=32dt+l31, k(local key)=16j+8h5+e
    short8 a_v[2][4];
#pragma unroll
    for (int dt = 0; dt < 2; ++dt)
#pragma unroll
      for (int j = 0; j < 4; ++j)
        a_v[dt][j] = *(const short8*)(V_lds[buf] +
            (((dt * 32 + l31) * 128 + j * 32 + h5 * 16) ^ swV));
    // ---- O^T += V^T · P^T
    __builtin_amdgcn_s_setprio(1);
#pragma unroll
    for (int j = 0; j < 4; ++j) {
      o_acc[0] = __builtin_amdgcn_mfma_f32_32x32x16_bf16(a_v[0][j], pb[j], o_acc[0], 0, 0, 0);
      o_acc[1] = __builtin_amdgcn_mfma_f32_32x32x16_bf16(a_v[1][j], pb[j], o_acc[1], 0, 0, 0);
    }
    __builtin_amdgcn_s_setprio(0);
    // ---- stage next tile, single barrier
    if (kb < 15) {
      int nb = buf ^ 1;
      *(uint4*)(K_lds[nb] + ((t * 16) ^ swrS)) = pk;
      *(uint4*)(V_lds[nb] + ((t * 16) ^ swrS)) = pv;
    }
    __syncthreads();
  }
  // ---- epilogue: y_t[b][s=q][ch=n*64+d], d=(r&3)+8(r>>2)+4h5+32dt
  int b_ = bn >> 3, n_ = bn & 7;
  float invl = 1.0f / l_run;
  __hip_bfloat16* yrow = y_t + (size_t)b_ * 524288 + (size_t)q * 512 + n_ * 64 + h5 * 4;
#pragma unroll
  for (int dt = 0; dt < 2; ++dt) {
#pragma unroll
    for (int g4 = 0; g4 < 4; ++g4) {  // reg groups of 4 -> d base {0,8,16,24}
      uint2 pr;
      pr.x = cvt_pk(o_acc[dt][4 * g4 + 0] * invl, o_acc[dt][4 * g4 + 1] * invl);
      pr.y = cvt_pk(o_acc[dt][4 * g4 + 2] * invl, o_acc[dt][4 * g4 + 3] * invl);
      *(uint2*)(yrow + dt * 32 + g4 * 8) = pr;
    }
  }
}

// ---------------------------------------------------------------------------
extern "C" void kernel_launch(void* const* d_in, const int* in_sizes, int n_in,
                              void* d_out, int out_size, void* d_ws, size_t ws_size,
                              hipStream_t stream) {
  const float* x      = (const float*)d_in[0];  // [16][512][1024]
  const float* w_attn = (const float*)d_in[1];  // [1536][512]
  const float* w_proj = (const float*)d_in[2];  // [512][512]
  float* out = (float*)d_out;

  // workspace (bf16 elements, ~104 MB total)
  __hip_bfloat16* wn_attn = (__hip_bfloat16*)d_ws;        // 1536*512
  __hip_bfloat16* wn_proj = wn_attn + 786432;             // 512*512
  __hip_bfloat16* x_t     = wn_proj + 262144;             // 16*1024*512
  __hip_bfloat16* v_ds    = x_t;                          // alias (x_t dead after gemm<0>)
  __hip_bfloat16* xp      = x_t + 8388608;                // 16*1536*1024 bf16
  __hip_bfloat16* y_t     = xp;                           // alias (xp dead after norm_pack)
  __hip_bfloat16* q_sd    = xp + 25165824;                // 16*8*1024*64
  __hip_bfloat16* k_sd    = q_sd + 8388608;

  wnorm_kernel<<<dim3(2048), dim3(256), 0, stream>>>(w_attn, w_proj, wn_attn, wn_proj);
  xt_kernel<<<dim3(16, 8, 16), dim3(256), 0, stream>>>(x, x_t);
  gemm_bf16<0><<<dim3(8, 12, 16), dim3(256), 0, stream>>>(wn_attn, x_t, xp, nullptr, 1536);
  norm_pack<<<dim3(16, 3, 16), dim3(256), 0, stream>>>(xp, q_sd, k_sd, v_ds);
  attn_mfma<<<dim3(128, 4), dim3(512), 0, stream>>>(q_sd, k_sd, v_ds, y_t);
  gemm_bf16<1><<<dim3(8, 4, 16), dim3(256), 0, stream>>>(wn_proj, y_t, out, x, 512);
}

// Round 10
// 158.443 us; speedup vs baseline: 1.3720x; 1.0285x over previous
//
#include <hip/hip_runtime.h>
#include <hip/hip_bf16.h>

// ---------------------------------------------------------------------------
// CosineAttention forward.  b=16, c=512, h=w=32 -> seq=1024, heads=8, hd=64.
//
// Pipeline (matmuls bf16 MFMA, fp32 accumulate):
//  1) wnorm_kernel : normalized bf16 w_attn (1536x512), w_proj (512x512)
//  2) xt_kernel    : x fp32 [b][c][s] -> x_t bf16 [b][s][c]
//  3) gemm_bf16<0> : xp[b][1536][1024] bf16 = wn_attn @ x   (B = x_t)
//  4) norm_pack    : fused pixel_norm + repack: q_sd,k_sd bf16 [bn][s][d]
//                    (Q gets 0.125*log2e), v_ds bf16 [bn][d][s]
//  5) attn_mfma    : flash attention, 32x32x16 MFMA, P fully in-register via
//                    KEY-PERMUTED QK^T (pi swaps key bits 2<->3 -> PV B-frag
//                    lane-local). MAX-FREE softmax: pixel_norm bounds
//                    |s_log2| <= 92.4 < 126, so p = exp2(s) raw is safe.
//                    K/V LDS dbuf, setprio, XCD-local grid; y_t [b][s][ch]
//  6) gemm_bf16<1> : out = mp_add(x, wn_proj @ y)           (B = y_t)
// ---------------------------------------------------------------------------

typedef __attribute__((ext_vector_type(8))) short short8;
typedef __attribute__((ext_vector_type(4))) float f32x4;
typedef __attribute__((ext_vector_type(16))) float f32x16;
typedef __attribute__((ext_vector_type(4))) unsigned short ushort4_t;
typedef __attribute__((ext_vector_type(4))) unsigned int uint4_t;

__device__ inline unsigned short f2bf(float v) {
  __hip_bfloat16 h = __float2bfloat16(v);
  return *reinterpret_cast<unsigned short*>(&h);
}
__device__ inline float bf2f(unsigned short u) {
  return __uint_as_float((unsigned)u << 16);
}
__device__ inline unsigned cvt_pk(float lo, float hi) {
  unsigned r;
  asm("v_cvt_pk_bf16_f32 %0, %1, %2" : "=v"(r) : "v"(lo), "v"(hi));
  return r;
}
__device__ inline void gload16(const void* g, void* l) {
  __builtin_amdgcn_global_load_lds(
      (const __attribute__((address_space(1))) unsigned int*)g,
      (__attribute__((address_space(3))) unsigned int*)l, 16, 0, 0);
}

// ---------------- weight normalization (bf16 out) --------------------------
__global__ __launch_bounds__(256) void wnorm_kernel(
    const float* __restrict__ wa, const float* __restrict__ wp,
    __hip_bfloat16* __restrict__ wna, __hip_bfloat16* __restrict__ wnp) {
  int o = blockIdx.x;
  const float* src;
  __hip_bfloat16* dst;
  if (o < 1536) { src = wa + (size_t)o * 512; dst = wna + (size_t)o * 512; }
  else          { src = wp + (size_t)(o - 1536) * 512; dst = wnp + (size_t)(o - 1536) * 512; }
  int tid = threadIdx.x;
  float a = src[tid], b = src[tid + 256];
  float ss = a * a + b * b;
#pragma unroll
  for (int off = 32; off > 0; off >>= 1) ss += __shfl_down(ss, off, 64);
  __shared__ float wsum[4];
  if ((tid & 63) == 0) wsum[tid >> 6] = ss;
  __syncthreads();
  float tot = wsum[0] + wsum[1] + wsum[2] + wsum[3];
  float r = 1.0f / (sqrtf(tot) + 2.2627416997969522e-3f);  // n + EPS*sqrt(512)
  dst[tid] = __float2bfloat16(a * r);
  dst[tid + 256] = __float2bfloat16(b * r);
}

// ---------------- x -> bf16 [b][s][c] transpose ----------------------------
__global__ __launch_bounds__(256) void xt_kernel(
    const float* __restrict__ x, __hip_bfloat16* __restrict__ xt) {
  __shared__ __align__(16) unsigned short trans[64][68];
  int s0 = blockIdx.x * 64, c0 = blockIdx.y * 64, b = blockIdx.z;
  int t = threadIdx.x;
  int sl = t & 63, cg = t >> 6;
  const float* src = x + (size_t)b * 524288 + (size_t)(c0 + cg * 16) * 1024 + s0 + sl;
#pragma unroll
  for (int i = 0; i < 16; i += 2) {
    float v0 = src[(size_t)i * 1024];
    float v1 = src[(size_t)(i + 1) * 1024];
    *(unsigned*)&trans[sl][cg * 16 + i] = (unsigned)f2bf(v0) | ((unsigned)f2bf(v1) << 16);
  }
  __syncthreads();
  int sw = t >> 2, cw = (t & 3) * 16;
  __hip_bfloat16* dst = xt + (size_t)b * 524288 + (size_t)(s0 + sw) * 512 + c0 + cw;
  uint2 r0 = *(uint2*)&trans[sw][cw + 0];
  uint2 r1 = *(uint2*)&trans[sw][cw + 4];
  uint2 r2 = *(uint2*)&trans[sw][cw + 8];
  uint2 r3 = *(uint2*)&trans[sw][cw + 12];
  uint4 o0 = {r0.x, r0.y, r1.x, r1.y};
  uint4 o1 = {r2.x, r2.y, r3.x, r3.y};
  *(uint4*)dst = o0;
  *(uint4*)((char*)dst + 16) = o1;
}

// ---------------- bf16 MFMA GEMM:  Out[b][M][1024] = A[Mx512] @ B[b]^T -----
// MODE 0: Out bf16 (QKV).  MODE 1: Out fp32 = mp_add(resid, acc).
template <int MODE>
__global__ __launch_bounds__(256) void gemm_bf16(
    const __hip_bfloat16* __restrict__ A, const __hip_bfloat16* __restrict__ B,
    void* __restrict__ Outv, const float* __restrict__ resid, int M) {
  __shared__ __align__(16) char Al[2][16384];
  __shared__ __align__(16) char Bl[2][16384];
  int t = threadIdx.x;
  int w = t >> 6, l = t & 63;
  int l15 = l & 15, lg = l >> 4;
  int wm = w >> 1, wn = w & 1;
  int n0 = blockIdx.x * 128, m0 = blockIdx.y * 128, b = blockIdx.z;
  const char* Ab = (const char*)A + (size_t)m0 * 1024;
  const char* Bb = (const char*)B + (size_t)b * 1048576 + (size_t)n0 * 1024;
  int rl = t >> 3;
  int soff = ((t & 7) * 16) ^ ((rl & 7) << 4);
  const char* asrc = Ab + (size_t)rl * 1024 + soff;
  const char* bsrc = Bb + (size_t)rl * 1024 + soff;

#define STAGE(bi, k0b)                                                    \
  do {                                                                    \
    _Pragma("unroll") for (int i = 0; i < 4; ++i) {                       \
      gload16(asrc + (size_t)i * 32768 + (k0b), Al[bi] + i * 4096 + w * 1024); \
      gload16(bsrc + (size_t)i * 32768 + (k0b), Bl[bi] + i * 4096 + w * 1024); \
    }                                                                     \
  } while (0)

  f32x4 acc[4][4];
#pragma unroll
  for (int mi = 0; mi < 4; ++mi)
#pragma unroll
    for (int ni = 0; ni < 4; ++ni) acc[mi][ni] = (f32x4){0.f, 0.f, 0.f, 0.f};

  STAGE(0, 0);
  __syncthreads();

  for (int ks = 0; ks < 8; ++ks) {
    int buf = ks & 1;
    if (ks < 7) STAGE(buf ^ 1, (ks + 1) * 128);
    short8 af[4][2], bf[4][2];
#pragma unroll
    for (int mi = 0; mi < 4; ++mi) {
      int row = wm * 64 + mi * 16 + l15;
      int sw = (row & 7) << 4;
#pragma unroll
      for (int h = 0; h < 2; ++h)
        af[mi][h] = *(const short8*)(Al[buf] + row * 128 + ((h * 64 + lg * 16) ^ sw));
    }
#pragma unroll
    for (int ni = 0; ni < 4; ++ni) {
      int row = wn * 64 + ni * 16 + l15;
      int sw = (row & 7) << 4;
#pragma unroll
      for (int h = 0; h < 2; ++h)
        bf[ni][h] = *(const short8*)(Bl[buf] + row * 128 + ((h * 64 + lg * 16) ^ sw));
    }
    __builtin_amdgcn_s_setprio(1);
#pragma unroll
    for (int mi = 0; mi < 4; ++mi)
#pragma unroll
      for (int ni = 0; ni < 4; ++ni) {
        acc[mi][ni] = __builtin_amdgcn_mfma_f32_16x16x32_bf16(af[mi][0], bf[ni][0], acc[mi][ni], 0, 0, 0);
        acc[mi][ni] = __builtin_amdgcn_mfma_f32_16x16x32_bf16(af[mi][1], bf[ni][1], acc[mi][ni], 0, 0, 0);
      }
    __builtin_amdgcn_s_setprio(0);
    if (ks < 7) __syncthreads();
  }
#undef STAGE

  if (MODE == 0) {
    unsigned short* outb = (unsigned short*)Outv + (size_t)b * M * 1024;
#pragma unroll
    for (int mi = 0; mi < 4; ++mi) {
      int row = m0 + wm * 64 + mi * 16 + lg * 4;
#pragma unroll
      for (int r = 0; r < 4; ++r) {
        unsigned short* orow = outb + (size_t)(row + r) * 1024 + n0 + wn * 64 + l15;
#pragma unroll
        for (int ni = 0; ni < 4; ++ni) orow[ni * 16] = f2bf(acc[mi][ni][r]);
      }
    }
  } else {
    float* outb = (float*)Outv + (size_t)b * M * 1024;
    const float* rb = resid + (size_t)b * M * 1024;
#pragma unroll
    for (int mi = 0; mi < 4; ++mi) {
      int row = m0 + wm * 64 + mi * 16 + lg * 4;
#pragma unroll
      for (int r = 0; r < 4; ++r) {
        float* orow = outb + (size_t)(row + r) * 1024 + n0 + wn * 64 + l15;
        const float* rrow = rb + (size_t)(row + r) * 1024 + n0 + wn * 64 + l15;
#pragma unroll
        for (int ni = 0; ni < 4; ++ni)
          orow[ni * 16] = 0.9191450300180578f * rrow[ni * 16] +
                          0.39391929857916763f * acc[mi][ni][r];
      }
    }
  }
}

// ---------------- fused pixel_norm + repack ---------------------------------
__global__ __launch_bounds__(256) void norm_pack(
    const __hip_bfloat16* __restrict__ xp,
    __hip_bfloat16* __restrict__ q_sd, __hip_bfloat16* __restrict__ k_sd,
    __hip_bfloat16* __restrict__ v_ds) {
  __shared__ __align__(16) unsigned short trans[64][68];
  int s0 = blockIdx.x * 64, g = blockIdx.y, b = blockIdx.z;
  int t = threadIdx.x;
  int s16 = t & 15, dg = t >> 4;
  int sl4 = s16 * 4;
  const unsigned short* src = (const unsigned short*)xp +
      (size_t)(b * 1536 + g * 512) * 1024 + s0 + sl4;
  float qm = (g == 0) ? 0.18033688011112042f : 1.0f;  // 0.125*log2(e) in Q

  ushort4_t raw[8][4];
  float f[4][4];
#pragma unroll
  for (int i = 0; i < 4; ++i) {
    int d = dg * 4 + i;
    float ss0 = 0.f, ss1 = 0.f, ss2 = 0.f, ss3 = 0.f;
#pragma unroll
    for (int n = 0; n < 8; ++n) {
      ushort4_t pk = *(const ushort4_t*)(src + (size_t)(n * 64 + d) * 1024);
      raw[n][i] = pk;
      float v0 = bf2f(pk[0]), v1 = bf2f(pk[1]), v2 = bf2f(pk[2]), v3 = bf2f(pk[3]);
      ss0 += v0 * v0; ss1 += v1 * v1; ss2 += v2 * v2; ss3 += v3 * v3;
    }
    f[i][0] = rsqrtf(ss0 * 0.125f + 1e-4f) * qm;
    f[i][1] = rsqrtf(ss1 * 0.125f + 1e-4f) * qm;
    f[i][2] = rsqrtf(ss2 * 0.125f + 1e-4f) * qm;
    f[i][3] = rsqrtf(ss3 * 0.125f + 1e-4f) * qm;
  }

  if (g == 2) {
#pragma unroll
    for (int n = 0; n < 8; ++n) {
      unsigned short* dst = (unsigned short*)v_ds +
          (size_t)((b * 8 + n) * 64) * 1024 + s0 + sl4;
#pragma unroll
      for (int i = 0; i < 4; ++i) {
        int d = dg * 4 + i;
        ushort4_t o;
#pragma unroll
        for (int j = 0; j < 4; ++j) o[j] = f2bf(bf2f(raw[n][i][j]) * f[i][j]);
        *(ushort4_t*)(dst + (size_t)d * 1024) = o;
      }
    }
    return;
  }

  unsigned short* dst0 = (unsigned short*)(g ? k_sd : q_sd) + (size_t)(b * 8) * 65536;
#pragma unroll 1
  for (int n = 0; n < 8; ++n) {
#pragma unroll
    for (int i = 0; i < 4; i += 2) {
#pragma unroll
      for (int j = 0; j < 4; ++j) {
        unsigned short lo = f2bf(bf2f(raw[n][i][j]) * f[i][j]);
        unsigned short hi = f2bf(bf2f(raw[n][i + 1][j]) * f[i + 1][j]);
        *(unsigned*)&trans[sl4 + j][dg * 4 + i] = (unsigned)lo | ((unsigned)hi << 16);
      }
    }
    __syncthreads();
    {
      const unsigned short* rs = &trans[t >> 2][(t & 3) * 16];
      uint2 r0 = *(const uint2*)(rs + 0);
      uint2 r1 = *(const uint2*)(rs + 4);
      uint2 r2 = *(const uint2*)(rs + 8);
      uint2 r3 = *(const uint2*)(rs + 12);
      unsigned short* dst = dst0 + (size_t)n * 65536 +
          (size_t)(s0 + (t >> 2)) * 64 + (t & 3) * 16;
      uint4 o0 = {r0.x, r0.y, r1.x, r1.y};
      uint4 o1 = {r2.x, r2.y, r3.x, r3.y};
      *(uint4*)dst = o0;
      *(uint4*)(dst + 8) = o1;
    }
    __syncthreads();
  }
}

// ---------------- flash attention, 32x32x16 MFMA, in-register P ------------
// Grid (bn=128 FAST -> XCD-local, qb=4). 8 waves/512 thr; wave w owns 32 q
// (q = qb*256 + w*32 + l31). Swapped operands: S'^T = mfma(K[pi(row)], Q^T),
// pi swaps key bits 2<->3 so the PV B-frag is LANE-LOCAL (no exchange).
// MAX-FREE softmax: |s_log2| <= 0.1803*512 = 92.4 < 126 (pixel_norm bound)
// so exp2(s) never overflows/underflows-to-zero; p = exp2(s) raw, l summed
// per-half, single cross-half shfl at the end. No rescale, no fmax tree.
__global__ __launch_bounds__(512, 4) void attn_mfma(
    const __hip_bfloat16* __restrict__ q_sd, const __hip_bfloat16* __restrict__ k_sd,
    const __hip_bfloat16* __restrict__ v_ds, __hip_bfloat16* __restrict__ y_t) {
  __shared__ __align__(16) char K_lds[2][8192];
  __shared__ __align__(16) char V_lds[2][8192];
  int t = threadIdx.x;
  int w = t >> 6, l = t & 63;
  int l31 = l & 31, h5 = l >> 5;
  int swV = (l31 & 7) << 4;                       // V frag read swizzle
  int pl = (l31 & 0x13) | ((l31 & 4) << 1) | ((l31 & 8) >> 1);  // swap bits 2,3
  int swK = (pl & 7) << 4;                        // K frag read swizzle (pi row)
  int bn = blockIdx.x, qb = blockIdx.y;
  const char* qg = (const char*)(q_sd + (size_t)bn * 65536);   // [s][d]
  const char* kg = (const char*)(k_sd + (size_t)bn * 65536);   // [s][d]
  const char* vg = (const char*)(v_ds + (size_t)bn * 65536);   // [d][s]

  // Q B-frags (32x32x16): col=q=l31, k = h5*8+e within 16-d kstep j
  int q = qb * 256 + w * 32 + l31;
  short8 bq[4];
#pragma unroll
  for (int j = 0; j < 4; ++j)
    bq[j] = *(const short8*)(qg + (size_t)q * 128 + j * 32 + h5 * 16);

  f32x16 o_acc[2];
#pragma unroll
  for (int r = 0; r < 16; ++r) { o_acc[0][r] = 0.f; o_acc[1][r] = 0.f; }
  float l_run = 0.f;

  // staging: 512 threads x 16B = one 8KB tile each for K and V
  int rowS = t >> 3;
  int offS = (t & 7) * 16;
  int swrS = (rowS & 7) << 4;
  {
    uint4 a = *(const uint4*)(kg + (size_t)t * 16);
    uint4 b2 = *(const uint4*)(vg + (size_t)rowS * 2048 + offS);
    *(uint4*)(K_lds[0] + ((t * 16) ^ swrS)) = a;
    *(uint4*)(V_lds[0] + ((t * 16) ^ swrS)) = b2;
  }
  __syncthreads();

  for (int kb = 0; kb < 16; ++kb) {
    int buf = kb & 1;
    uint4 pk, pv;
    if (kb < 15) {  // prefetch next tile (in flight across softmax+PV)
      pk = *(const uint4*)(kg + (size_t)(kb + 1) * 8192 + (size_t)t * 16);
      pv = *(const uint4*)(vg + (size_t)rowS * 2048 + (size_t)(kb + 1) * 128 + offS);
    }
    // ---- K A-frags with pi-permuted rows: row = 32kt + pl
    short8 a_k[2][4];
#pragma unroll
    for (int kt = 0; kt < 2; ++kt)
#pragma unroll
      for (int j = 0; j < 4; ++j)
        a_k[kt][j] = *(const short8*)(K_lds[buf] +
            (((kt * 32 + pl) * 128 + j * 32 + h5 * 16) ^ swK));
    // ---- S'^T = K_pi · Q^T
    f32x16 s0, s1;
#pragma unroll
    for (int r = 0; r < 16; ++r) { s0[r] = 0.f; s1[r] = 0.f; }
    __builtin_amdgcn_s_setprio(1);
#pragma unroll
    for (int j = 0; j < 4; ++j) {
      s0 = __builtin_amdgcn_mfma_f32_32x32x16_bf16(a_k[0][j], bq[j], s0, 0, 0, 0);
      s1 = __builtin_amdgcn_mfma_f32_32x32x16_bf16(a_k[1][j], bq[j], s1, 0, 0, 0);
    }
    __builtin_amdgcn_s_setprio(0);
    // ---- P = exp2(S') raw (max-free; bound guarantees finite, nonzero sum)
    unsigned W0[8], W1[8];
    float ts = 0.f;
#pragma unroll
    for (int m = 0; m < 8; ++m) {
      float p0 = exp2f(s0[2 * m]), p1 = exp2f(s0[2 * m + 1]);
      float p2 = exp2f(s1[2 * m]), p3 = exp2f(s1[2 * m + 1]);
      ts += (p0 + p1) + (p2 + p3);
      W0[m] = cvt_pk(p0, p1);
      W1[m] = cvt_pk(p2, p3);
    }
    l_run += ts;
    // ---- PV B-frags are lane-local thanks to pi: pb[j] = W[4(j&1)..+3]
    short8 pb[4];
#pragma unroll
    for (int j = 0; j < 4; ++j) {
      uint4_t pw;
      if (j == 0)      pw = (uint4_t){W0[0], W0[1], W0[2], W0[3]};
      else if (j == 1) pw = (uint4_t){W0[4], W0[5], W0[6], W0[7]};
      else if (j == 2) pw = (uint4_t){W1[0], W1[1], W1[2], W1[3]};
      else             pw = (uint4_t){W1[4], W1[5], W1[6], W1[7]};
      pb[j] = __builtin_bit_cast(short8, pw);
    }
    // ---- V A-frags: row=d=32dt+l31, k(local key)=16j+8h5+e
    short8 a_v[2][4];
#pragma unroll
    for (int dt = 0; dt < 2; ++dt)
#pragma unroll
      for (int j = 0; j < 4; ++j)
        a_v[dt][j] = *(const short8*)(V_lds[buf] +
            (((dt * 32 + l31) * 128 + j * 32 + h5 * 16) ^ swV));
    // ---- O^T += V^T · P^T
    __builtin_amdgcn_s_setprio(1);
#pragma unroll
    for (int j = 0; j < 4; ++j) {
      o_acc[0] = __builtin_amdgcn_mfma_f32_32x32x16_bf16(a_v[0][j], pb[j], o_acc[0], 0, 0, 0);
      o_acc[1] = __builtin_amdgcn_mfma_f32_32x32x16_bf16(a_v[1][j], pb[j], o_acc[1], 0, 0, 0);
    }
    __builtin_amdgcn_s_setprio(0);
    // ---- stage next tile, single barrier
    if (kb < 15) {
      int nb = buf ^ 1;
      *(uint4*)(K_lds[nb] + ((t * 16) ^ swrS)) = pk;
      *(uint4*)(V_lds[nb] + ((t * 16) ^ swrS)) = pv;
    }
    __syncthreads();
  }
  // ---- epilogue: y_t[b][s=q][ch=n*64+d], d=(r&3)+8(r>>2)+4h5+32dt
  int b_ = bn >> 3, n_ = bn & 7;
  float lsum = l_run + __shfl_xor(l_run, 32, 64);  // single cross-half combine
  float invl = 1.0f / lsum;
  __hip_bfloat16* yrow = y_t + (size_t)b_ * 524288 + (size_t)q * 512 + n_ * 64 + h5 * 4;
#pragma unroll
  for (int dt = 0; dt < 2; ++dt) {
#pragma unroll
    for (int g4 = 0; g4 < 4; ++g4) {  // reg groups of 4 -> d base {0,8,16,24}
      uint2 pr;
      pr.x = cvt_pk(o_acc[dt][4 * g4 + 0] * invl, o_acc[dt][4 * g4 + 1] * invl);
      pr.y = cvt_pk(o_acc[dt][4 * g4 + 2] * invl, o_acc[dt][4 * g4 + 3] * invl);
      *(uint2*)(yrow + dt * 32 + g4 * 8) = pr;
    }
  }
}

// ---------------------------------------------------------------------------
extern "C" void kernel_launch(void* const* d_in, const int* in_sizes, int n_in,
                              void* d_out, int out_size, void* d_ws, size_t ws_size,
                              hipStream_t stream) {
  const float* x      = (const float*)d_in[0];  // [16][512][1024]
  const float* w_attn = (const float*)d_in[1];  // [1536][512]
  const float* w_proj = (const float*)d_in[2];  // [512][512]
  float* out = (float*)d_out;

  // workspace (bf16 elements, ~104 MB total)
  __hip_bfloat16* wn_attn = (__hip_bfloat16*)d_ws;        // 1536*512
  __hip_bfloat16* wn_proj = wn_attn + 786432;             // 512*512
  __hip_bfloat16* x_t     = wn_proj + 262144;             // 16*1024*512
  __hip_bfloat16* v_ds    = x_t;                          // alias (x_t dead after gemm<0>)
  __hip_bfloat16* xp      = x_t + 8388608;                // 16*1536*1024 bf16
  __hip_bfloat16* y_t     = xp;                           // alias (xp dead after norm_pack)
  __hip_bfloat16* q_sd    = xp + 25165824;                // 16*8*1024*64
  __hip_bfloat16* k_sd    = q_sd + 8388608;

  wnorm_kernel<<<dim3(2048), dim3(256), 0, stream>>>(w_attn, w_proj, wn_attn, wn_proj);
  xt_kernel<<<dim3(16, 8, 16), dim3(256), 0, stream>>>(x, x_t);
  gemm_bf16<0><<<dim3(8, 12, 16), dim3(256), 0, stream>>>(wn_attn, x_t, xp, nullptr, 1536);
  norm_pack<<<dim3(16, 3, 16), dim3(256), 0, stream>>>(xp, q_sd, k_sd, v_ds);
  attn_mfma<<<dim3(128, 4), dim3(512), 0, stream>>>(q_sd, k_sd, v_ds, y_t);
  gemm_bf16<1><<<dim3(8, 4, 16), dim3(256), 0, stream>>>(wn_proj, y_t, out, x, 512);
}